// Round 13
// baseline (238.016 us; speedup 1.0000x reference)
//
#include <hip/hip_runtime.h>
#include <math.h>

// ---------------- constants from the reference ----------------
#define NCLS 10
#define TOPK 1000
#define DETS 100
#define CANDMAX 4096
#define SLOTS 16   // 16 * 64 lanes = 1024 >= TOPK (full fallback)
#define ACTK 256   // fast-path active set: 4 slots * 64 lanes

// max-logit binning: monotone 2-segment map, 256 bins.
// bin 0 = gated (m <= MGATE, score <= ~0.05). Seg A (MGATE,2.2] -> 1..160,
// seg B (2.2, ~4.5] -> 161..255 (0.024 logit/bin at the selection region).
#define NB2 256
#define MGATE (-2.9444389791664403f)   // ln(0.05/0.95)
#define SEAM 2.2f
#define SCA 30.907200f                  // 159 / (SEAM - MGATE)
#define SCB 41.0f
#define NBLKB 256  // blocks per image for the bins pass (TLP: 8 blocks/CU)

__device__ __forceinline__ float sigmoidf_(float x) {
    return 1.0f / (1.0f + expf(-x));
}

__device__ __forceinline__ int mbin_(float m) {
    if (!(m > MGATE)) return 0;
    int b;
    if (m > SEAM) { b = 161 + (int)((m - SEAM) * SCB); if (b > 255) b = 255; }
    else          { b = 1 + (int)((m - MGATE) * SCA);  if (b > 160) b = 160; }
    return b;
}

__device__ __forceinline__ float key_score(const unsigned long long* key, int c) {
    return __uint_as_float(~(unsigned)(key[c] >> 32));
}

// order-isomorphic float<->u32 mapping (total order, bijective)
__device__ __forceinline__ unsigned fkey_(float f) {
    unsigned b = __float_as_uint(f);
    return (b & 0x80000000u) ? ~b : (b | 0x80000000u);
}
__device__ __forceinline__ float funkey_(unsigned k) {
    return __uint_as_float((k & 0x80000000u) ? (k & 0x7FFFFFFFu) : ~k);
}

// 64-lane unsigned max via DPP (row_shr 1/2/4/8 + row_bcast15/31), ~ALU latency.
__device__ __forceinline__ unsigned wave_umax_(unsigned x) {
    unsigned t;
    t = (unsigned)__builtin_amdgcn_update_dpp(0, (int)x, 0x111, 0xF, 0xF, false); x = (x > t) ? x : t;
    t = (unsigned)__builtin_amdgcn_update_dpp(0, (int)x, 0x112, 0xF, 0xF, false); x = (x > t) ? x : t;
    t = (unsigned)__builtin_amdgcn_update_dpp(0, (int)x, 0x114, 0xF, 0xF, false); x = (x > t) ? x : t;
    t = (unsigned)__builtin_amdgcn_update_dpp(0, (int)x, 0x118, 0xF, 0xF, false); x = (x > t) ? x : t;
    t = (unsigned)__builtin_amdgcn_update_dpp(0, (int)x, 0x142, 0xF, 0xF, false); x = (x > t) ? x : t;
    t = (unsigned)__builtin_amdgcn_update_dpp(0, (int)x, 0x143, 0xF, 0xF, false); x = (x > t) ? x : t;
    return (unsigned)__builtin_amdgcn_readlane((int)x, 63);
}

// K1: max-logit -> bin (NO expf), DIRECT contiguous quad loads (one address,
// 10 dwordx4 at immediate offsets; TLP from NBLKB=256 hides latency — R12
// showed TLP, not coalescing, was the limiter). x4 LDS sub-hists, last-block
// findP via done counter.
__global__ __launch_bounds__(256) void k_score_bins(const float* __restrict__ logits,
                                                    unsigned char* __restrict__ binc,
                                                    unsigned* hist,
                                                    unsigned* __restrict__ done,
                                                    unsigned* __restrict__ P,
                                                    int A) {
    __shared__ unsigned h[4][NB2];         // 4 KB
    __shared__ int s_last;
    int img = blockIdx.y;
    int tid = threadIdx.x;
    for (int i = tid; i < 4 * NB2; i += 256) ((unsigned*)h)[i] = 0;
    __syncthreads();

    const float* base = logits + (size_t)img * A * NCLS;
    unsigned char* bc = binc + (size_t)img * A;
    int rep = tid & 3;

    int nquad = A >> 2;
    for (int q = blockIdx.x * 256 + tid; q < nquad; q += NBLKB * 256) {
        const float4* lp = (const float4*)(base + (size_t)q * 40);
        float f[40];
#pragma unroll
        for (int i = 0; i < 10; ++i) ((float4*)f)[i] = lp[i];
        unsigned ub = 0;
#pragma unroll
        for (int j = 0; j < 4; ++j) {
            float m = f[10 * j];
#pragma unroll
            for (int c = 1; c < 10; ++c) m = fmaxf(m, f[10 * j + c]);
            int b = mbin_(m);
            ub |= ((unsigned)b) << (8 * j);
            if (b) atomicAdd(&h[rep][b], 1u);
        }
        *(unsigned*)(bc + (size_t)q * 4) = ub;
    }
    // tail anchors (A % 4), block x==0 only
    if (blockIdx.x == 0) {
        for (int a = (nquad << 2) + tid; a < A; a += 256) {
            const float* lp2 = base + (size_t)a * NCLS;
            float m = lp2[0];
            for (int c = 1; c < 10; ++c) m = fmaxf(m, lp2[c]);
            int b = mbin_(m);
            bc[a] = (unsigned char)b;
            if (b) atomicAdd(&h[rep][b], 1u);
        }
    }
    __syncthreads();
    for (int i = tid; i < NB2; i += 256) {
        unsigned c = h[0][i] + h[1][i] + h[2][i] + h[3][i];
        if (c) atomicAdd(&hist[(size_t)img * NB2 + i], c);
    }
    __syncthreads();
    if (tid == 0) {
        __threadfence();   // hist atomics ordered before done increment
        unsigned old = atomicAdd(&done[img], 1u);
        s_last = (old == (unsigned)(NBLKB - 1)) ? 1 : 0;
    }
    __syncthreads();
    // last finishing block: smallest bin with suffix count >= TOPK
    if (s_last && tid < 64) {
        int lane = tid;
        unsigned* hh = hist + (size_t)img * NB2;
        unsigned b4[4];
        unsigned s = 0;
#pragma unroll
        for (int j = 0; j < 4; ++j) { b4[j] = atomicAdd(&hh[lane * 4 + j], 0u); s += b4[j]; }
        unsigned suf = s;
#pragma unroll
        for (int d = 1; d < 64; d <<= 1) {
            unsigned o = __shfl_down(suf, d);
            if (lane + d < 64) suf += o;
        }
        unsigned above = __shfl_down(suf, 1);
        if (lane == 63) above = 0;
        if (lane == 0 && suf < (unsigned)TOPK) P[img] = 0u;  // pathological fallback
        if (above < (unsigned)TOPK && suf >= (unsigned)TOPK) {
            unsigned cum = above;
            for (int j = 3; j >= 0; --j) {
                cum += b4[j];
                if (cum >= (unsigned)TOPK) { P[img] = (unsigned)(lane * 4 + j); break; }
            }
        }
    }
}

// K2 (fused): bin-scan compaction -> key build -> hybrid-barrier bitonic sort
// -> decode -> soft-NMS (DPP-argmax, exact) -> greedy NMS -> top-100 emit.
// Sort barriers: a pass needs s_barrier only if j>=64 (cross-wave reads) or
// the previous pass had j>=64 (reads cross-wave writes). Other passes exchange
// strictly within one wave (threads t and t^j share a wave for j<64; same for
// the +1024 twin elements) — same-wave LDS ops execute in program order on
// CDNA, so a compiler-only fence suffices.
__global__ __launch_bounds__(1024) void k_sortnms(const unsigned char* __restrict__ binc,
                                                  const unsigned* __restrict__ P,
                                                  const float* __restrict__ logits,
                                                  const float* __restrict__ rel,
                                                  const float* __restrict__ anch,
                                                  float* __restrict__ out, int A, int B) {
    __shared__ unsigned long long key[CANDMAX];
    __shared__ float s_box[TOPK][4];
    __shared__ int   s_lab[TOPK];
    __shared__ float s_pbox[TOPK][4];
    __shared__ int   s_plab[TOPK];
    __shared__ float s_psc[TOPK];
    __shared__ int   s_alive[TOPK];
    __shared__ unsigned s_n;

    const float CLIPV = 4.135166556742356f;  // log(1000/16)
    const float EPS = 1e-7f;
    const float W_ = 1333.0f, H_ = 800.0f;

    int img = blockIdx.x;
    int tid = threadIdx.x;
    const float* base = logits + (size_t)img * A * NCLS;

    // ---- compaction phase 1: scan bins, collect candidate anchor indices ----
    if (tid == 0) s_n = 0;
    __syncthreads();
    {
        unsigned p = P[img];
        unsigned psel = p ? (p - 1u) : 0u;
        const unsigned* b4 = (const unsigned*)(binc + (size_t)img * A);
        int nquad = A >> 2;
        int nq4 = nquad >> 2;
        for (int g = tid; g < nq4; g += 1024) {
            uint4 u = ((const uint4*)b4)[g];
            unsigned ws[4] = {u.x, u.y, u.z, u.w};
#pragma unroll
            for (int w2 = 0; w2 < 4; ++w2) {
                unsigned ub = ws[w2];
#pragma unroll
                for (int j = 0; j < 4; ++j) {
                    unsigned bj = (ub >> (8 * j)) & 0xFFu;
                    if ((psel == 0u) || (bj >= psel)) {
                        unsigned pos = atomicAdd(&s_n, 1u);
                        if (pos < CANDMAX)
                            key[pos] = (unsigned long long)(unsigned)((g * 4 + w2) * 4 + j);
                    }
                }
            }
        }
        for (int q = (nq4 << 2) + tid; q < nquad; q += 1024) {
            unsigned ub = b4[q];
#pragma unroll
            for (int j = 0; j < 4; ++j) {
                unsigned bj = (ub >> (8 * j)) & 0xFFu;
                if ((psel == 0u) || (bj >= psel)) {
                    unsigned pos = atomicAdd(&s_n, 1u);
                    if (pos < CANDMAX)
                        key[pos] = (unsigned long long)(unsigned)(q * 4 + j);
                }
            }
        }
        for (int a = (nquad << 2) + tid; a < A; a += 1024) {
            unsigned bj = binc[(size_t)img * A + a];
            if ((psel == 0u) || (bj >= psel)) {
                unsigned pos = atomicAdd(&s_n, 1u);
                if (pos < CANDMAX)
                    key[pos] = (unsigned long long)(unsigned)a;
            }
        }
    }
    __syncthreads();
    unsigned n = s_n;
    if (n > CANDMAX) n = CANDMAX;
    int L = (n <= 1024) ? 1024 : (n <= 2048) ? 2048 : CANDMAX;

    // ---- phase 2: gather logits, build exact keys; pad the rest ----
    for (int t2 = tid; t2 < (int)n; t2 += 1024) {
        unsigned a = (unsigned)key[t2];
        const float* lp = base + (size_t)a * NCLS;
        float m = lp[0];
#pragma unroll
        for (int c = 1; c < 10; ++c) m = fmaxf(m, lp[c]);
        float sc = sigmoidf_(m);           // == max(sigmoid(l_c)): monotone
        sc = (sc > 0.05f) ? sc : 0.0f;     // exact old gate for the key
        unsigned bits = __float_as_uint(sc);
        key[t2] = ((unsigned long long)(~bits) << 32) | a;
    }
    for (int i = (int)n + tid; i < CANDMAX; i += 1024) key[i] = ~0ull;
    __syncthreads();

    // ---- sort phase (ascending => best score first, then lowest index) ----
    {
        bool prev_cross = false;   // the __syncthreads above covers pass 1
        for (int k = 2; k <= L; k <<= 1) {
            for (int j = k >> 1; j > 0; j >>= 1) {
                bool cross = (j >= 64);
                if (cross || prev_cross) __syncthreads();
                else asm volatile("" ::: "memory");   // wave-local pass
                for (int i = tid; i < L; i += 1024) {
                    int l = i ^ j;
                    if (l > i) {
                        unsigned long long va = key[i], vb = key[l];
                        bool up = ((i & k) == 0);
                        if (up ? (va > vb) : (va < vb)) { key[i] = vb; key[l] = va; }
                    }
                }
                prev_cross = cross;
            }
        }
    }
    __syncthreads();

    // ---- Phase A (1024 threads, 1 candidate each): decode into LDS ----
    if (tid < TOPK) {
        unsigned long long ik = key[tid];
        unsigned ai = (unsigned)ik;
        if (ai >= (unsigned)A) ai = 0;
        const float* lp = base + (size_t)ai * NCLS;
        float best = sigmoidf_(lp[0]); int lbb = 0;
#pragma unroll
        for (int cc = 1; cc < NCLS; ++cc) {
            float v = sigmoidf_(lp[cc]);
            if (v > best) { best = v; lbb = cc; }
        }
        const float* rp = rel + ((size_t)img * A + ai) * 4;
        const float* ap = anch + (size_t)ai * 4;
        float a0 = ap[0], a1 = ap[1], a2 = ap[2], a3 = ap[3];
        float wa = a2 - a0, ha = a3 - a1;
        float cxa = a0 + 0.5f * wa, cya = a1 + 0.5f * ha;
        float dx = rp[0], dy = rp[1];
        float dw = fminf(rp[2], CLIPV), dh = fminf(rp[3], CLIPV);
        float cx = dx * wa + cxa, cy = dy * ha + cya;
        float w = expf(dw) * wa, h = expf(dh) * ha;
        s_box[tid][0] = fminf(fmaxf(cx - 0.5f * w, 0.0f), W_);
        s_box[tid][1] = fminf(fmaxf(cy - 0.5f * h, 0.0f), H_);
        s_box[tid][2] = fminf(fmaxf(cx + 0.5f * w, 0.0f), W_);
        s_box[tid][3] = fminf(fmaxf(cy + 0.5f * h, 0.0f), H_);
        s_lab[tid] = lbb;
    }
    __syncthreads();
    if (tid >= 64) return;          // wave 0 only from here; no more barriers
    int lane = tid;

    int M = TOPK;
    int need_full = 0;
    float bound = key_score(key, ACTK);   // init score of first EXCLUDED cand

    // ================= FAST ATTEMPT: DPP-argmax, 4 slots =================
    {
        float sc[4], x1[4], y1[4], x2[4], y2[4], ar[4];
        int lb[4];
#pragma unroll
        for (int j = 0; j < 4; ++j) {
            int c = lane + (j << 6);
            float4 bb = *(const float4*)&s_box[c][0];
            x1[j] = bb.x; y1[j] = bb.y; x2[j] = bb.z; y2[j] = bb.w;
            ar[j] = (bb.z - bb.x) * (bb.w - bb.y);
            lb[j] = s_lab[c];
            sc[j] = key_score(key, c);
        }

        int nconf = 0, Mf = -1;

        for (int t = 0; t < ACTK; ++t) {
            float bv = sc[0]; int bj = 0;
#pragma unroll
            for (int j = 1; j < 4; ++j)
                if (sc[j] > bv) { bv = sc[j]; bj = j; }
            unsigned mk = fkey_(bv);
            unsigned mx = wave_umax_(mk);          // uniform SGPR result
            float pcur = funkey_(mx);

            if (!(pcur >= bound)) { need_full = 1; break; }

            int pick = -1;
#pragma unroll
            for (int jj = 0; jj < 4; ++jj) {
                if (pick < 0) {
                    unsigned long long mj = __ballot(mk == mx && bj == jj);
                    if (mj) pick = (jj << 6) + (__ffsll(mj) - 1);
                }
            }

            float psc = fmaxf(pcur, 0.0f);
            float4 pb = *(const float4*)&s_box[pick][0];
            int plab_ = s_lab[pick];
            if (lane == 0) {
                *(float4*)&s_pbox[t][0] = pb;
                s_plab[t] = plab_;
                s_psc[t] = psc;
            }

            float4 qb[4]; int ga[4];
#pragma unroll
            for (int k = 0; k < 4; ++k) {
                int p = lane + (k << 6);
                int pc2 = (p < t) ? p : 0;
                qb[k] = *(const float4*)&s_pbox[pc2][0];
                ga[k] = (p < t) ? s_alive[pc2] : 0;
            }

            float wax = (pb.z - pb.x) * (pb.w - pb.y);
#pragma unroll
            for (int j = 0; j < 4; ++j) {
                float lx2 = fmaxf(pb.x, x1[j]), ly2 = fmaxf(pb.y, y1[j]);
                float rx2 = fminf(pb.z, x2[j]), ry2 = fminf(pb.w, y2[j]);
                float iw2 = fmaxf(rx2 - lx2, 0.0f), ih2 = fmaxf(ry2 - ly2, 0.0f);
                float inter2 = iw2 * ih2;
                bool hot = (inter2 > 0.0f) && (lb[j] == plab_);
                if (__ballot(hot) != 0ull) {
                    float iou2 = inter2 / (wax + ar[j] - inter2 + EPS);
                    float ie = (lb[j] == plab_) ? iou2 : 0.0f;
                    sc[j] *= expf(-(ie * ie) / 0.5f);
                }
            }
#pragma unroll
            for (int j = 0; j < 4; ++j)
                if (lane + (j << 6) == pick) sc[j] = -1.0f;

            bool sup = false;
#pragma unroll
            for (int k = 0; k < 4; ++k) {
                if (ga[k]) {
                    float lx = fmaxf(pb.x, qb[k].x), ly = fmaxf(pb.y, qb[k].y);
                    float rx = fminf(pb.z, qb[k].z), ry = fminf(pb.w, qb[k].w);
                    float iw = fmaxf(rx - lx, 0.0f), ih = fmaxf(ry - ly, 0.0f);
                    float inter = iw * ih;
                    float qa = (qb[k].z - qb[k].x) * (qb[k].w - qb[k].y);
                    float iou = inter / (wax + qa - inter + EPS);
                    sup = sup || (iou > 0.8f);
                }
            }
            bool alive = (psc > 0.3f) && (__ballot(sup) == 0ull);
            if (lane == 0) s_alive[t] = alive ? 1 : 0;
            nconf += alive ? 1 : 0;
            if (nconf >= DETS) { Mf = t + 1; break; }
        }
        if (!need_full) {
            if (Mf < 0) need_full = 1;   // exhausted 256 picks with <100 dets
            else M = Mf;
        }
    }

    // ================= FULL FALLBACK: verbatim 16-slot loop =================
    if (need_full) {
        float sc[SLOTS], x1[SLOTS], y1[SLOTS], x2[SLOTS], y2[SLOTS], ar[SLOTS];
        int lb[SLOTS];
#pragma unroll
        for (int j = 0; j < SLOTS; ++j) {
            int c = lane + (j << 6);
            if (c < TOPK) {
                float4 bb = *(const float4*)&s_box[c][0];
                x1[j] = bb.x; y1[j] = bb.y; x2[j] = bb.z; y2[j] = bb.w;
                ar[j] = (bb.z - bb.x) * (bb.w - bb.y);
                lb[j] = s_lab[c];
                sc[j] = key_score(key, c);
            } else {
                sc[j] = -2.0f; lb[j] = -1;
                x1[j] = y1[j] = x2[j] = y2[j] = ar[j] = 0.0f;
            }
        }
        unsigned long long aw = 0;
        if (lane < 15) aw = ~0ull;
        else if (lane == 15) aw = (1ull << (TOPK - 15 * 64)) - 1;
        int f = 0, nconf = 0;
        M = TOPK;
        for (int t = 0; t < TOPK; ++t) {
            int fp = (f < TOPK) ? f : 0;
            float4 fb = *(const float4*)&s_box[fp][0];
            int flab = s_lab[fp];
            int fs = f >> 6;
            float v = sc[0];
#pragma unroll
            for (int j = 1; j < SLOTS; ++j) if (fs == j) v = sc[j];
            float cf = __shfl(v, f & 63);
            float lm = sc[0];
#pragma unroll
            for (int j = 1; j < SLOTS; ++j) lm = fmaxf(lm, sc[j]);
            int pick; float pcur; float4 pb; int plab_;
            unsigned long long bb2 = __ballot(lm > cf);
            if (bb2 == 0) {
                pick = f; pcur = cf; pb = fb; plab_ = flab;
            } else {
                float bv = sc[0]; int bi = lane;
#pragma unroll
                for (int j = 1; j < SLOTS; ++j) {
                    int e = lane + (j << 6);
                    if (sc[j] > bv) { bv = sc[j]; bi = e; }
                }
#pragma unroll
                for (int d = 32; d; d >>= 1) {
                    float ov = __shfl_xor(bv, d);
                    int oi = __shfl_xor(bi, d);
                    if (ov > bv || (ov == bv && oi < bi)) { bv = ov; bi = oi; }
                }
                pick = bi; pcur = bv;
                pb = *(const float4*)&s_box[pick][0];
                plab_ = s_lab[pick];
            }
            float psc = fmaxf(pcur, 0.0f);
            if (lane == 0) {
                *(float4*)&s_pbox[t][0] = pb;
                s_plab[t] = plab_;
                s_psc[t] = psc;
            }
            bool alive = (psc > 0.3f);
            if (alive && t > 0) {
                float pa = (pb.z - pb.x) * (pb.w - pb.y);
                int kprev = ((t - 1) >> 6) + 1;
                bool sup = false;
                for (int k = 0; k < kprev; ++k) {
                    int p = lane + (k << 6);
                    int pc = (p < t) ? p : 0;
                    float4 qb = *(const float4*)&s_pbox[pc][0];
                    int ga = s_alive[pc];
                    if (p < t && ga) {
                        float lx = fmaxf(pb.x, qb.x), ly = fmaxf(pb.y, qb.y);
                        float rx = fminf(pb.z, qb.z), ry = fminf(pb.w, qb.w);
                        float iw = fmaxf(rx - lx, 0.0f), ih = fmaxf(ry - ly, 0.0f);
                        float inter = iw * ih;
                        float qa = (qb.z - qb.x) * (qb.w - qb.y);
                        float iou = inter / (pa + qa - inter + EPS);
                        sup = sup || (iou > 0.8f);
                    }
                }
                alive = (__ballot(sup) == 0ull);
            }
            if (lane == 0) s_alive[t] = alive ? 1 : 0;
            nconf += alive ? 1 : 0;
            if (nconf >= DETS) { M = t + 1; break; }
            float wax = (pb.z - pb.x) * (pb.w - pb.y);
#pragma unroll
            for (int j = 0; j < SLOTS; ++j) {
                float lx2 = fmaxf(pb.x, x1[j]), ly2 = fmaxf(pb.y, y1[j]);
                float rx2 = fminf(pb.z, x2[j]), ry2 = fminf(pb.w, y2[j]);
                float iw2 = fmaxf(rx2 - lx2, 0.0f), ih2 = fmaxf(ry2 - ly2, 0.0f);
                float inter2 = iw2 * ih2;
                bool hot = (inter2 > 0.0f) && (lb[j] == plab_);
                if (__ballot(hot) != 0ull) {
                    float iou2 = inter2 / (wax + ar[j] - inter2 + EPS);
                    float ie = (lb[j] == plab_) ? iou2 : 0.0f;
                    sc[j] *= expf(-(ie * ie) / 0.5f);
                }
            }
#pragma unroll
            for (int j = 0; j < SLOTS; ++j)
                if (lane + (j << 6) == pick) sc[j] = -1.0f;
            if (lane == (pick >> 6)) aw &= ~(1ull << (pick & 63));
            if (pick == f) {
                int fw = f >> 6;
                unsigned long long w2 = __shfl(aw, fw);
                while (w2 == 0ull && fw < 15) { ++fw; w2 = __shfl(aw, fw); }
                f = (w2 == 0ull) ? TOPK : (fw << 6) + (__ffsll(w2) - 1);
            }
        }
    }

    // ---- emit: alive picks in pick order, then dead padding if needed ----
    float* out_boxes  = out;
    float* out_scores = out + (size_t)B * DETS * 4;
    float* out_labels = out + (size_t)B * DETS * 5;
    int kmax = (M + 63) >> 6;
    int base2 = 0;
    for (int k = 0; k < kmax; ++k) {
        int p = lane + (k << 6);
        bool av = (p < M) && (s_alive[p] != 0);
        unsigned long long mask = __ballot(av);
        int slot = base2 + (int)__popcll(mask & ((1ull << lane) - 1ull));
        if (av && slot < DETS) {
            float4 pb = *(const float4*)&s_pbox[p][0];
            float* ob = out_boxes + ((size_t)img * DETS + slot) * 4;
            ob[0] = pb.x; ob[1] = pb.y; ob[2] = pb.z; ob[3] = pb.w;
            out_scores[img * DETS + slot] = s_psc[p];
            out_labels[img * DETS + slot] = (float)s_plab[p];
        }
        base2 += (int)__popcll(mask);
    }
    if (base2 < DETS) {
        int dbase = 0;
        for (int k = 0; k < kmax; ++k) {
            int p = lane + (k << 6);
            bool dd = (p < M) && (s_alive[p] == 0);
            unsigned long long mask = __ballot(dd);
            int slot = base2 + dbase + (int)__popcll(mask & ((1ull << lane) - 1ull));
            if (dd && slot < DETS) {
                float4 pb = *(const float4*)&s_pbox[p][0];
                float* ob = out_boxes + ((size_t)img * DETS + slot) * 4;
                ob[0] = pb.x; ob[1] = pb.y; ob[2] = pb.z; ob[3] = pb.w;
                out_scores[img * DETS + slot] = -1.0f;
                out_labels[img * DETS + slot] = (float)s_plab[p];
            }
            dbase += (int)__popcll(mask);
        }
    }
}

extern "C" void kernel_launch(void* const* d_in, const int* in_sizes, int n_in,
                              void* d_out, int out_size, void* d_ws, size_t ws_size,
                              hipStream_t stream) {
    const float* logits = (const float*)d_in[0];
    const float* rel = (const float*)d_in[1];
    const float* anch = (const float*)d_in[2];
    float* out = (float*)d_out;

    int A = in_sizes[2] / 4;                 // anchors
    int B = in_sizes[0] / (A * NCLS);        // batch

    // workspace: [hist | done] zeroed in ONE memset; then P, bins (~1.6MB).
    char* w = (char*)d_ws;
    unsigned* hist = (unsigned*)w;           w += (size_t)B * NB2 * 4;
    unsigned* done = (unsigned*)w;           w += (size_t)B * 4;
    size_t zbytes = (size_t)(w - (char*)d_ws);
    unsigned* P = (unsigned*)w;              w += (size_t)B * 4;
    unsigned char* binc = (unsigned char*)w;

    hipMemsetAsync(d_ws, 0, zbytes, stream);

    dim3 g1(NBLKB, (unsigned)B);
    k_score_bins<<<g1, 256, 0, stream>>>(logits, binc, hist, done, P, A);
    k_sortnms<<<B, 1024, 0, stream>>>(binc, P, logits, rel, anch, out, A, B);
}

// Round 14
// 230.399 us; speedup vs baseline: 1.0331x; 1.0331x over previous
//
#include <hip/hip_runtime.h>
#include <math.h>

// ---------------- constants from the reference ----------------
#define NCLS 10
#define TOPK 1000
#define DETS 100
#define CANDMAX 4096
#define SLOTS 16   // 16 * 64 lanes = 1024 >= TOPK (full fallback)
#define ACTK 256   // fast-path active set: 4 slots * 64 lanes
#define TILE 256   // anchors staged per block-iteration in k_score_bins

// max-logit binning: monotone 2-segment map, 256 bins.
// bin 0 = gated (m <= MGATE, score <= ~0.05). Seg A (MGATE,2.2] -> 1..160,
// seg B (2.2, ~4.5] -> 161..255 (0.024 logit/bin at the selection region).
#define NB2 256
#define MGATE (-2.9444389791664403f)   // ln(0.05/0.95)
#define SEAM 2.2f
#define SCA 30.907200f                  // 159 / (SEAM - MGATE)
#define SCB 41.0f
#define NBLKB 256  // blocks per image for the bins pass (TLP: 8 blocks/CU)

__device__ __forceinline__ float sigmoidf_(float x) {
    return 1.0f / (1.0f + expf(-x));
}

__device__ __forceinline__ int mbin_(float m) {
    if (!(m > MGATE)) return 0;
    int b;
    if (m > SEAM) { b = 161 + (int)((m - SEAM) * SCB); if (b > 255) b = 255; }
    else          { b = 1 + (int)((m - MGATE) * SCA);  if (b > 160) b = 160; }
    return b;
}

__device__ __forceinline__ float key_score(const unsigned long long* key, int c) {
    return __uint_as_float(~(unsigned)(key[c] >> 32));
}

// order-isomorphic float<->u32 mapping (total order, bijective)
__device__ __forceinline__ unsigned fkey_(float f) {
    unsigned b = __float_as_uint(f);
    return (b & 0x80000000u) ? ~b : (b | 0x80000000u);
}
__device__ __forceinline__ float funkey_(unsigned k) {
    return __uint_as_float((k & 0x80000000u) ? (k & 0x7FFFFFFFu) : ~k);
}

// 64-lane unsigned max via DPP (row_shr 1/2/4/8 + row_bcast15/31), ~ALU latency.
__device__ __forceinline__ unsigned wave_umax_(unsigned x) {
    unsigned t;
    t = (unsigned)__builtin_amdgcn_update_dpp(0, (int)x, 0x111, 0xF, 0xF, false); x = (x > t) ? x : t;
    t = (unsigned)__builtin_amdgcn_update_dpp(0, (int)x, 0x112, 0xF, 0xF, false); x = (x > t) ? x : t;
    t = (unsigned)__builtin_amdgcn_update_dpp(0, (int)x, 0x114, 0xF, 0xF, false); x = (x > t) ? x : t;
    t = (unsigned)__builtin_amdgcn_update_dpp(0, (int)x, 0x118, 0xF, 0xF, false); x = (x > t) ? x : t;
    t = (unsigned)__builtin_amdgcn_update_dpp(0, (int)x, 0x142, 0xF, 0xF, false); x = (x > t) ? x : t;
    t = (unsigned)__builtin_amdgcn_update_dpp(0, (int)x, 0x143, 0xF, 0xF, false); x = (x > t) ? x : t;
    return (unsigned)__builtin_amdgcn_readlane((int)x, 63);
}

// K1: max-logit -> bin (NO expf), LDS-transpose tile staging (R12-measured
// best together with NBLKB=256), uchar bin cache, x4 LDS sub-hists,
// last-block findP via done counter.
__global__ __launch_bounds__(256) void k_score_bins(const float* __restrict__ logits,
                                                    unsigned char* __restrict__ binc,
                                                    unsigned* hist,
                                                    unsigned* __restrict__ done,
                                                    unsigned* __restrict__ P,
                                                    int A) {
    __shared__ float tilef[TILE * NCLS];   // 10 KB
    __shared__ unsigned h[4][NB2];         // 4 KB
    __shared__ int s_last;
    int img = blockIdx.y;
    int tid = threadIdx.x;
    for (int i = tid; i < 4 * NB2; i += 256) ((unsigned*)h)[i] = 0;
    __syncthreads();

    const float* base = logits + (size_t)img * A * NCLS;
    unsigned char* bc = binc + (size_t)img * A;
    int rep = tid & 3;

    int ntile = A / TILE;   // full tiles; remainder handled by tail path
    for (int tile = blockIdx.x; tile < ntile; tile += NBLKB) {
        const float4* src = (const float4*)(base + (size_t)tile * TILE * NCLS); // 640 f4
        float4 v0 = src[tid];
        float4 v1 = src[256 + tid];
        float4 v2;
        if (tid < 128) v2 = src[512 + tid];
        ((float4*)tilef)[tid] = v0;
        ((float4*)tilef)[256 + tid] = v1;
        if (tid < 128) ((float4*)tilef)[512 + tid] = v2;
        __syncthreads();
        float m = tilef[tid * 10];
#pragma unroll
        for (int c = 1; c < 10; ++c) m = fmaxf(m, tilef[tid * 10 + c]);
        int b = mbin_(m);
        bc[(size_t)tile * TILE + tid] = (unsigned char)b;
        if (b) atomicAdd(&h[rep][b], 1u);
        __syncthreads();   // protect tile before next overwrite
    }
    // tail anchors (A % TILE), block x==0 only
    if (blockIdx.x == 0) {
        for (int a = ntile * TILE + tid; a < A; a += 256) {
            const float* lp2 = base + (size_t)a * NCLS;
            float m = lp2[0];
            for (int c = 1; c < 10; ++c) m = fmaxf(m, lp2[c]);
            int b = mbin_(m);
            bc[a] = (unsigned char)b;
            if (b) atomicAdd(&h[rep][b], 1u);
        }
    }
    __syncthreads();
    for (int i = tid; i < NB2; i += 256) {
        unsigned c = h[0][i] + h[1][i] + h[2][i] + h[3][i];
        if (c) atomicAdd(&hist[(size_t)img * NB2 + i], c);
    }
    __syncthreads();
    if (tid == 0) {
        __threadfence();   // hist atomics ordered before done increment
        unsigned old = atomicAdd(&done[img], 1u);
        s_last = (old == (unsigned)(NBLKB - 1)) ? 1 : 0;
    }
    __syncthreads();
    // last finishing block: smallest bin with suffix count >= TOPK
    if (s_last && tid < 64) {
        int lane = tid;
        unsigned* hh = hist + (size_t)img * NB2;
        unsigned b4[4];
        unsigned s = 0;
#pragma unroll
        for (int j = 0; j < 4; ++j) { b4[j] = atomicAdd(&hh[lane * 4 + j], 0u); s += b4[j]; }
        unsigned suf = s;
#pragma unroll
        for (int d = 1; d < 64; d <<= 1) {
            unsigned o = __shfl_down(suf, d);
            if (lane + d < 64) suf += o;
        }
        unsigned above = __shfl_down(suf, 1);
        if (lane == 63) above = 0;
        if (lane == 0 && suf < (unsigned)TOPK) P[img] = 0u;  // pathological fallback
        if (above < (unsigned)TOPK && suf >= (unsigned)TOPK) {
            unsigned cum = above;
            for (int j = 3; j >= 0; --j) {
                cum += b4[j];
                if (cum >= (unsigned)TOPK) { P[img] = (unsigned)(lane * 4 + j); break; }
            }
        }
    }
}

// K2 (fused): bin-scan compaction -> key build -> bitonic sort -> decode ->
// soft-NMS (DPP-argmax, exact) -> inline greedy NMS -> top-100 emit.
__global__ __launch_bounds__(1024) void k_sortnms(const unsigned char* __restrict__ binc,
                                                  const unsigned* __restrict__ P,
                                                  const float* __restrict__ logits,
                                                  const float* __restrict__ rel,
                                                  const float* __restrict__ anch,
                                                  float* __restrict__ out, int A, int B) {
    __shared__ unsigned long long key[CANDMAX];
    __shared__ float s_box[TOPK][4];
    __shared__ int   s_lab[TOPK];
    __shared__ float s_pbox[TOPK][4];
    __shared__ int   s_plab[TOPK];
    __shared__ float s_psc[TOPK];
    __shared__ int   s_alive[TOPK];
    __shared__ unsigned s_n;

    const float CLIPV = 4.135166556742356f;  // log(1000/16)
    const float EPS = 1e-7f;
    const float W_ = 1333.0f, H_ = 800.0f;

    int img = blockIdx.x;
    int tid = threadIdx.x;
    const float* base = logits + (size_t)img * A * NCLS;

    // ---- compaction phase 1: scan bins, collect candidate anchor indices ----
    if (tid == 0) s_n = 0;
    __syncthreads();
    {
        unsigned p = P[img];
        unsigned psel = p ? (p - 1u) : 0u;
        const unsigned* b4 = (const unsigned*)(binc + (size_t)img * A);
        int nquad = A >> 2;
        int nq4 = nquad >> 2;
        for (int g = tid; g < nq4; g += 1024) {
            uint4 u = ((const uint4*)b4)[g];
            unsigned ws[4] = {u.x, u.y, u.z, u.w};
#pragma unroll
            for (int w2 = 0; w2 < 4; ++w2) {
                unsigned ub = ws[w2];
#pragma unroll
                for (int j = 0; j < 4; ++j) {
                    unsigned bj = (ub >> (8 * j)) & 0xFFu;
                    if ((psel == 0u) || (bj >= psel)) {
                        unsigned pos = atomicAdd(&s_n, 1u);
                        if (pos < CANDMAX)
                            key[pos] = (unsigned long long)(unsigned)((g * 4 + w2) * 4 + j);
                    }
                }
            }
        }
        for (int q = (nq4 << 2) + tid; q < nquad; q += 1024) {
            unsigned ub = b4[q];
#pragma unroll
            for (int j = 0; j < 4; ++j) {
                unsigned bj = (ub >> (8 * j)) & 0xFFu;
                if ((psel == 0u) || (bj >= psel)) {
                    unsigned pos = atomicAdd(&s_n, 1u);
                    if (pos < CANDMAX)
                        key[pos] = (unsigned long long)(unsigned)(q * 4 + j);
                }
            }
        }
        for (int a = (nquad << 2) + tid; a < A; a += 1024) {
            unsigned bj = binc[(size_t)img * A + a];
            if ((psel == 0u) || (bj >= psel)) {
                unsigned pos = atomicAdd(&s_n, 1u);
                if (pos < CANDMAX)
                    key[pos] = (unsigned long long)(unsigned)a;
            }
        }
    }
    __syncthreads();
    unsigned n = s_n;
    if (n > CANDMAX) n = CANDMAX;
    int L = (n <= 1024) ? 1024 : (n <= 2048) ? 2048 : CANDMAX;

    // ---- phase 2: gather logits, build exact keys; pad the rest ----
    for (int t2 = tid; t2 < (int)n; t2 += 1024) {
        unsigned a = (unsigned)key[t2];
        const float* lp = base + (size_t)a * NCLS;
        float m = lp[0];
#pragma unroll
        for (int c = 1; c < 10; ++c) m = fmaxf(m, lp[c]);
        float sc = sigmoidf_(m);           // == max(sigmoid(l_c)): monotone
        sc = (sc > 0.05f) ? sc : 0.0f;     // exact old gate for the key
        unsigned bits = __float_as_uint(sc);
        key[t2] = ((unsigned long long)(~bits) << 32) | a;
    }
    for (int i = (int)n + tid; i < CANDMAX; i += 1024) key[i] = ~0ull;
    __syncthreads();

    // ---- sort phase (ascending => best score first, then lowest index) ----
    for (int k = 2; k <= L; k <<= 1) {
        for (int j = k >> 1; j > 0; j >>= 1) {
            for (int i = tid; i < L; i += 1024) {
                int l = i ^ j;
                if (l > i) {
                    unsigned long long va = key[i], vb = key[l];
                    bool up = ((i & k) == 0);
                    if (up ? (va > vb) : (va < vb)) { key[i] = vb; key[l] = va; }
                }
            }
            __syncthreads();
        }
    }

    // ---- Phase A (1024 threads, 1 candidate each): decode into LDS ----
    if (tid < TOPK) {
        unsigned long long ik = key[tid];
        unsigned ai = (unsigned)ik;
        if (ai >= (unsigned)A) ai = 0;
        const float* lp = base + (size_t)ai * NCLS;
        float best = sigmoidf_(lp[0]); int lbb = 0;
#pragma unroll
        for (int cc = 1; cc < NCLS; ++cc) {
            float v = sigmoidf_(lp[cc]);
            if (v > best) { best = v; lbb = cc; }
        }
        const float* rp = rel + ((size_t)img * A + ai) * 4;
        const float* ap = anch + (size_t)ai * 4;
        float a0 = ap[0], a1 = ap[1], a2 = ap[2], a3 = ap[3];
        float wa = a2 - a0, ha = a3 - a1;
        float cxa = a0 + 0.5f * wa, cya = a1 + 0.5f * ha;
        float dx = rp[0], dy = rp[1];
        float dw = fminf(rp[2], CLIPV), dh = fminf(rp[3], CLIPV);
        float cx = dx * wa + cxa, cy = dy * ha + cya;
        float w = expf(dw) * wa, h = expf(dh) * ha;
        s_box[tid][0] = fminf(fmaxf(cx - 0.5f * w, 0.0f), W_);
        s_box[tid][1] = fminf(fmaxf(cy - 0.5f * h, 0.0f), H_);
        s_box[tid][2] = fminf(fmaxf(cx + 0.5f * w, 0.0f), W_);
        s_box[tid][3] = fminf(fmaxf(cy + 0.5f * h, 0.0f), H_);
        s_lab[tid] = lbb;
    }
    __syncthreads();
    if (tid >= 64) return;          // wave 0 only from here; no more barriers
    int lane = tid;

    int M = TOPK;
    int need_full = 0;
    float bound = key_score(key, ACTK);   // init score of first EXCLUDED cand

    // ================= FAST ATTEMPT: DPP-argmax, 4 slots =================
    {
        float sc[4], x1[4], y1[4], x2[4], y2[4], ar[4];
        int lb[4];
#pragma unroll
        for (int j = 0; j < 4; ++j) {
            int c = lane + (j << 6);
            float4 bb = *(const float4*)&s_box[c][0];
            x1[j] = bb.x; y1[j] = bb.y; x2[j] = bb.z; y2[j] = bb.w;
            ar[j] = (bb.z - bb.x) * (bb.w - bb.y);
            lb[j] = s_lab[c];
            sc[j] = key_score(key, c);
        }

        int nconf = 0, Mf = -1;

        for (int t = 0; t < ACTK; ++t) {
            float bv = sc[0]; int bj = 0;
#pragma unroll
            for (int j = 1; j < 4; ++j)
                if (sc[j] > bv) { bv = sc[j]; bj = j; }
            unsigned mk = fkey_(bv);
            unsigned mx = wave_umax_(mk);          // uniform SGPR result
            float pcur = funkey_(mx);

            if (!(pcur >= bound)) { need_full = 1; break; }

            // lowest-index winner, branch-free: 4 independent ballots + cselects
            bool el = (mk == mx);
            unsigned long long m0 = __ballot(el && bj == 0);
            unsigned long long m1 = __ballot(el && bj == 1);
            unsigned long long m2 = __ballot(el && bj == 2);
            unsigned long long m3 = __ballot(el && bj == 3);
            int pick = m0 ? (__ffsll(m0) - 1)
                     : m1 ? (64 + __ffsll(m1) - 1)
                     : m2 ? (128 + __ffsll(m2) - 1)
                     :      (192 + __ffsll(m3) - 1);

            float psc = fmaxf(pcur, 0.0f);
            float4 pb = *(const float4*)&s_box[pick][0];
            int plab_ = s_lab[pick];
            if (lane == 0) {
                *(float4*)&s_pbox[t][0] = pb;
                s_plab[t] = plab_;
                s_psc[t] = psc;
            }

            // ---- greedy loads issued early (static unroll, clamped addrs) ----
            float4 qb[4]; int ga[4];
#pragma unroll
            for (int k = 0; k < 4; ++k) {
                int p = lane + (k << 6);
                int pc2 = (p < t) ? p : 0;
                qb[k] = *(const float4*)&s_pbox[pc2][0];
                ga[k] = (p < t) ? s_alive[pc2] : 0;
            }

            // ---- decay (ballot-skip: divide+expf only when a lane is hot) ----
            float wax = (pb.z - pb.x) * (pb.w - pb.y);
#pragma unroll
            for (int j = 0; j < 4; ++j) {
                float lx2 = fmaxf(pb.x, x1[j]), ly2 = fmaxf(pb.y, y1[j]);
                float rx2 = fminf(pb.z, x2[j]), ry2 = fminf(pb.w, y2[j]);
                float iw2 = fmaxf(rx2 - lx2, 0.0f), ih2 = fmaxf(ry2 - ly2, 0.0f);
                float inter2 = iw2 * ih2;
                bool hot = (inter2 > 0.0f) && (lb[j] == plab_);
                if (__ballot(hot) != 0ull) {
                    float iou2 = inter2 / (wax + ar[j] - inter2 + EPS);
                    float ie = (lb[j] == plab_) ? iou2 : 0.0f;
                    sc[j] *= expf(-(ie * ie) / 0.5f);
                }
                // skipped slots/lanes: factor would be expf(-0.0f)==1.0f exactly
            }
            // mark picked (after decay, matching the verified ordering)
#pragma unroll
            for (int j = 0; j < 4; ++j)
                if (lane + (j << 6) == pick) sc[j] = -1.0f;

            // ---- greedy compares + ballot (loads landed under decay) ----
            bool sup = false;
#pragma unroll
            for (int k = 0; k < 4; ++k) {
                if (ga[k]) {
                    float lx = fmaxf(pb.x, qb[k].x), ly = fmaxf(pb.y, qb[k].y);
                    float rx = fminf(pb.z, qb[k].z), ry = fminf(pb.w, qb[k].w);
                    float iw = fmaxf(rx - lx, 0.0f), ih = fmaxf(ry - ly, 0.0f);
                    float inter = iw * ih;
                    float qa = (qb[k].z - qb[k].x) * (qb[k].w - qb[k].y);
                    float iou = inter / (wax + qa - inter + EPS);
                    sup = sup || (iou > 0.8f);
                }
            }
            bool alive = (psc > 0.3f) && (__ballot(sup) == 0ull);
            if (lane == 0) s_alive[t] = alive ? 1 : 0;
            nconf += alive ? 1 : 0;
            if (nconf >= DETS) { Mf = t + 1; break; }
        }
        if (!need_full) {
            if (Mf < 0) need_full = 1;   // exhausted 256 picks with <100 dets
            else M = Mf;
        }
    }

    // ================= FULL FALLBACK: verbatim 16-slot loop =================
    if (need_full) {
        float sc[SLOTS], x1[SLOTS], y1[SLOTS], x2[SLOTS], y2[SLOTS], ar[SLOTS];
        int lb[SLOTS];
#pragma unroll
        for (int j = 0; j < SLOTS; ++j) {
            int c = lane + (j << 6);
            if (c < TOPK) {
                float4 bb = *(const float4*)&s_box[c][0];
                x1[j] = bb.x; y1[j] = bb.y; x2[j] = bb.z; y2[j] = bb.w;
                ar[j] = (bb.z - bb.x) * (bb.w - bb.y);
                lb[j] = s_lab[c];
                sc[j] = key_score(key, c);
            } else {
                sc[j] = -2.0f; lb[j] = -1;
                x1[j] = y1[j] = x2[j] = y2[j] = ar[j] = 0.0f;
            }
        }
        unsigned long long aw = 0;
        if (lane < 15) aw = ~0ull;
        else if (lane == 15) aw = (1ull << (TOPK - 15 * 64)) - 1;
        int f = 0, nconf = 0;
        M = TOPK;
        for (int t = 0; t < TOPK; ++t) {
            int fp = (f < TOPK) ? f : 0;
            float4 fb = *(const float4*)&s_box[fp][0];
            int flab = s_lab[fp];
            int fs = f >> 6;
            float v = sc[0];
#pragma unroll
            for (int j = 1; j < SLOTS; ++j) if (fs == j) v = sc[j];
            float cf = __shfl(v, f & 63);
            float lm = sc[0];
#pragma unroll
            for (int j = 1; j < SLOTS; ++j) lm = fmaxf(lm, sc[j]);
            int pick; float pcur; float4 pb; int plab_;
            unsigned long long bb2 = __ballot(lm > cf);
            if (bb2 == 0) {
                pick = f; pcur = cf; pb = fb; plab_ = flab;
            } else {
                float bv = sc[0]; int bi = lane;
#pragma unroll
                for (int j = 1; j < SLOTS; ++j) {
                    int e = lane + (j << 6);
                    if (sc[j] > bv) { bv = sc[j]; bi = e; }
                }
#pragma unroll
                for (int d = 32; d; d >>= 1) {
                    float ov = __shfl_xor(bv, d);
                    int oi = __shfl_xor(bi, d);
                    if (ov > bv || (ov == bv && oi < bi)) { bv = ov; bi = oi; }
                }
                pick = bi; pcur = bv;
                pb = *(const float4*)&s_box[pick][0];
                plab_ = s_lab[pick];
            }
            float psc = fmaxf(pcur, 0.0f);
            if (lane == 0) {
                *(float4*)&s_pbox[t][0] = pb;
                s_plab[t] = plab_;
                s_psc[t] = psc;
            }
            bool alive = (psc > 0.3f);
            if (alive && t > 0) {
                float pa = (pb.z - pb.x) * (pb.w - pb.y);
                int kprev = ((t - 1) >> 6) + 1;
                bool sup = false;
                for (int k = 0; k < kprev; ++k) {
                    int p = lane + (k << 6);
                    int pc = (p < t) ? p : 0;
                    float4 qb = *(const float4*)&s_pbox[pc][0];
                    int ga = s_alive[pc];
                    if (p < t && ga) {
                        float lx = fmaxf(pb.x, qb.x), ly = fmaxf(pb.y, qb.y);
                        float rx = fminf(pb.z, qb.z), ry = fminf(pb.w, qb.w);
                        float iw = fmaxf(rx - lx, 0.0f), ih = fmaxf(ry - ly, 0.0f);
                        float inter = iw * ih;
                        float qa = (qb.z - qb.x) * (qb.w - qb.y);
                        float iou = inter / (pa + qa - inter + EPS);
                        sup = sup || (iou > 0.8f);
                    }
                }
                alive = (__ballot(sup) == 0ull);
            }
            if (lane == 0) s_alive[t] = alive ? 1 : 0;
            nconf += alive ? 1 : 0;
            if (nconf >= DETS) { M = t + 1; break; }
            float wax = (pb.z - pb.x) * (pb.w - pb.y);
#pragma unroll
            for (int j = 0; j < SLOTS; ++j) {
                float lx2 = fmaxf(pb.x, x1[j]), ly2 = fmaxf(pb.y, y1[j]);
                float rx2 = fminf(pb.z, x2[j]), ry2 = fminf(pb.w, y2[j]);
                float iw2 = fmaxf(rx2 - lx2, 0.0f), ih2 = fmaxf(ry2 - ly2, 0.0f);
                float inter2 = iw2 * ih2;
                bool hot = (inter2 > 0.0f) && (lb[j] == plab_);
                if (__ballot(hot) != 0ull) {
                    float iou2 = inter2 / (wax + ar[j] - inter2 + EPS);
                    float ie = (lb[j] == plab_) ? iou2 : 0.0f;
                    sc[j] *= expf(-(ie * ie) / 0.5f);
                }
            }
#pragma unroll
            for (int j = 0; j < SLOTS; ++j)
                if (lane + (j << 6) == pick) sc[j] = -1.0f;
            if (lane == (pick >> 6)) aw &= ~(1ull << (pick & 63));
            if (pick == f) {
                int fw = f >> 6;
                unsigned long long w2 = __shfl(aw, fw);
                while (w2 == 0ull && fw < 15) { ++fw; w2 = __shfl(aw, fw); }
                f = (w2 == 0ull) ? TOPK : (fw << 6) + (__ffsll(w2) - 1);
            }
        }
    }

    // ---- emit: alive picks in pick order, then dead padding if needed ----
    float* out_boxes  = out;
    float* out_scores = out + (size_t)B * DETS * 4;
    float* out_labels = out + (size_t)B * DETS * 5;
    int kmax = (M + 63) >> 6;
    int base2 = 0;
    for (int k = 0; k < kmax; ++k) {
        int p = lane + (k << 6);
        bool av = (p < M) && (s_alive[p] != 0);
        unsigned long long mask = __ballot(av);
        int slot = base2 + (int)__popcll(mask & ((1ull << lane) - 1ull));
        if (av && slot < DETS) {
            float4 pb = *(const float4*)&s_pbox[p][0];
            float* ob = out_boxes + ((size_t)img * DETS + slot) * 4;
            ob[0] = pb.x; ob[1] = pb.y; ob[2] = pb.z; ob[3] = pb.w;
            out_scores[img * DETS + slot] = s_psc[p];
            out_labels[img * DETS + slot] = (float)s_plab[p];
        }
        base2 += (int)__popcll(mask);
    }
    if (base2 < DETS) {
        int dbase = 0;
        for (int k = 0; k < kmax; ++k) {
            int p = lane + (k << 6);
            bool dd = (p < M) && (s_alive[p] == 0);
            unsigned long long mask = __ballot(dd);
            int slot = base2 + dbase + (int)__popcll(mask & ((1ull << lane) - 1ull));
            if (dd && slot < DETS) {
                float4 pb = *(const float4*)&s_pbox[p][0];
                float* ob = out_boxes + ((size_t)img * DETS + slot) * 4;
                ob[0] = pb.x; ob[1] = pb.y; ob[2] = pb.z; ob[3] = pb.w;
                out_scores[img * DETS + slot] = -1.0f;
                out_labels[img * DETS + slot] = (float)s_plab[p];
            }
            dbase += (int)__popcll(mask);
        }
    }
}

extern "C" void kernel_launch(void* const* d_in, const int* in_sizes, int n_in,
                              void* d_out, int out_size, void* d_ws, size_t ws_size,
                              hipStream_t stream) {
    const float* logits = (const float*)d_in[0];
    const float* rel = (const float*)d_in[1];
    const float* anch = (const float*)d_in[2];
    float* out = (float*)d_out;

    int A = in_sizes[2] / 4;                 // anchors
    int B = in_sizes[0] / (A * NCLS);        // batch

    // workspace: [hist | done] zeroed in ONE memset; then P, bins (~1.6MB).
    char* w = (char*)d_ws;
    unsigned* hist = (unsigned*)w;           w += (size_t)B * NB2 * 4;
    unsigned* done = (unsigned*)w;           w += (size_t)B * 4;
    size_t zbytes = (size_t)(w - (char*)d_ws);
    unsigned* P = (unsigned*)w;              w += (size_t)B * 4;
    unsigned char* binc = (unsigned char*)w;

    hipMemsetAsync(d_ws, 0, zbytes, stream);

    dim3 g1(NBLKB, (unsigned)B);
    k_score_bins<<<g1, 256, 0, stream>>>(logits, binc, hist, done, P, A);
    k_sortnms<<<B, 1024, 0, stream>>>(binc, P, logits, rel, anch, out, A, B);
}

// Round 15
// 226.295 us; speedup vs baseline: 1.0518x; 1.0181x over previous
//
#include <hip/hip_runtime.h>
#include <math.h>

// ---------------- constants from the reference ----------------
#define NCLS 10
#define TOPK 1000
#define DETS 100
#define CANDMAX 4096
#define SLOTS 16   // 16 * 64 lanes = 1024 >= TOPK (full fallback)
#define ACTK 256   // fast-path active set: 4 slots * 64 lanes
#define TILE 256   // anchors staged per block-iteration in k_score_bins

// max-logit binning: monotone 2-segment map, 256 bins.
// bin 0 = gated (m <= MGATE, score <= ~0.05). Seg A (MGATE,2.2] -> 1..160,
// seg B (2.2, ~4.5] -> 161..255 (0.024 logit/bin at the selection region).
#define NB2 256
#define MGATE (-2.9444389791664403f)   // ln(0.05/0.95)
#define SEAM 2.2f
#define SCA 30.907200f                  // 159 / (SEAM - MGATE)
#define SCB 41.0f
#define NBLKB 256  // blocks per image for the bins pass (TLP: 8 blocks/CU)

__device__ __forceinline__ float sigmoidf_(float x) {
    return 1.0f / (1.0f + expf(-x));
}

__device__ __forceinline__ int mbin_(float m) {
    if (!(m > MGATE)) return 0;
    int b;
    if (m > SEAM) { b = 161 + (int)((m - SEAM) * SCB); if (b > 255) b = 255; }
    else          { b = 1 + (int)((m - MGATE) * SCA);  if (b > 160) b = 160; }
    return b;
}

__device__ __forceinline__ float key_score(const unsigned long long* key, int c) {
    return __uint_as_float(~(unsigned)(key[c] >> 32));
}

// order-isomorphic float<->u32 mapping (total order, bijective)
__device__ __forceinline__ unsigned fkey_(float f) {
    unsigned b = __float_as_uint(f);
    return (b & 0x80000000u) ? ~b : (b | 0x80000000u);
}
__device__ __forceinline__ float funkey_(unsigned k) {
    return __uint_as_float((k & 0x80000000u) ? (k & 0x7FFFFFFFu) : ~k);
}

// 64-lane unsigned max via DPP (row_shr 1/2/4/8 + row_bcast15/31), ~ALU latency.
__device__ __forceinline__ unsigned wave_umax_(unsigned x) {
    unsigned t;
    t = (unsigned)__builtin_amdgcn_update_dpp(0, (int)x, 0x111, 0xF, 0xF, false); x = (x > t) ? x : t;
    t = (unsigned)__builtin_amdgcn_update_dpp(0, (int)x, 0x112, 0xF, 0xF, false); x = (x > t) ? x : t;
    t = (unsigned)__builtin_amdgcn_update_dpp(0, (int)x, 0x114, 0xF, 0xF, false); x = (x > t) ? x : t;
    t = (unsigned)__builtin_amdgcn_update_dpp(0, (int)x, 0x118, 0xF, 0xF, false); x = (x > t) ? x : t;
    t = (unsigned)__builtin_amdgcn_update_dpp(0, (int)x, 0x142, 0xF, 0xF, false); x = (x > t) ? x : t;
    t = (unsigned)__builtin_amdgcn_update_dpp(0, (int)x, 0x143, 0xF, 0xF, false); x = (x > t) ? x : t;
    return (unsigned)__builtin_amdgcn_readlane((int)x, 63);
}

// K1: max-logit -> bin (NO expf), LDS-transpose tile staging (measured best
// together with NBLKB=256, R12), uchar bin cache, x4 LDS sub-hists,
// last-block findP via done counter.
__global__ __launch_bounds__(256) void k_score_bins(const float* __restrict__ logits,
                                                    unsigned char* __restrict__ binc,
                                                    unsigned* hist,
                                                    unsigned* __restrict__ done,
                                                    unsigned* __restrict__ P,
                                                    int A) {
    __shared__ float tilef[TILE * NCLS];   // 10 KB
    __shared__ unsigned h[4][NB2];         // 4 KB
    __shared__ int s_last;
    int img = blockIdx.y;
    int tid = threadIdx.x;
    for (int i = tid; i < 4 * NB2; i += 256) ((unsigned*)h)[i] = 0;
    __syncthreads();

    const float* base = logits + (size_t)img * A * NCLS;
    unsigned char* bc = binc + (size_t)img * A;
    int rep = tid & 3;

    int ntile = A / TILE;   // full tiles; remainder handled by tail path
    for (int tile = blockIdx.x; tile < ntile; tile += NBLKB) {
        const float4* src = (const float4*)(base + (size_t)tile * TILE * NCLS); // 640 f4
        float4 v0 = src[tid];
        float4 v1 = src[256 + tid];
        float4 v2;
        if (tid < 128) v2 = src[512 + tid];
        ((float4*)tilef)[tid] = v0;
        ((float4*)tilef)[256 + tid] = v1;
        if (tid < 128) ((float4*)tilef)[512 + tid] = v2;
        __syncthreads();
        float m = tilef[tid * 10];
#pragma unroll
        for (int c = 1; c < 10; ++c) m = fmaxf(m, tilef[tid * 10 + c]);
        int b = mbin_(m);
        bc[(size_t)tile * TILE + tid] = (unsigned char)b;
        if (b) atomicAdd(&h[rep][b], 1u);
        __syncthreads();   // protect tile before next overwrite
    }
    // tail anchors (A % TILE), block x==0 only
    if (blockIdx.x == 0) {
        for (int a = ntile * TILE + tid; a < A; a += 256) {
            const float* lp2 = base + (size_t)a * NCLS;
            float m = lp2[0];
            for (int c = 1; c < 10; ++c) m = fmaxf(m, lp2[c]);
            int b = mbin_(m);
            bc[a] = (unsigned char)b;
            if (b) atomicAdd(&h[rep][b], 1u);
        }
    }
    __syncthreads();
    for (int i = tid; i < NB2; i += 256) {
        unsigned c = h[0][i] + h[1][i] + h[2][i] + h[3][i];
        if (c) atomicAdd(&hist[(size_t)img * NB2 + i], c);
    }
    __syncthreads();
    if (tid == 0) {
        __threadfence();   // hist atomics ordered before done increment
        unsigned old = atomicAdd(&done[img], 1u);
        s_last = (old == (unsigned)(NBLKB - 1)) ? 1 : 0;
    }
    __syncthreads();
    // last finishing block: smallest bin with suffix count >= TOPK
    if (s_last && tid < 64) {
        int lane = tid;
        unsigned* hh = hist + (size_t)img * NB2;
        unsigned b4[4];
        unsigned s = 0;
#pragma unroll
        for (int j = 0; j < 4; ++j) { b4[j] = atomicAdd(&hh[lane * 4 + j], 0u); s += b4[j]; }
        unsigned suf = s;
#pragma unroll
        for (int d = 1; d < 64; d <<= 1) {
            unsigned o = __shfl_down(suf, d);
            if (lane + d < 64) suf += o;
        }
        unsigned above = __shfl_down(suf, 1);
        if (lane == 63) above = 0;
        if (lane == 0 && suf < (unsigned)TOPK) P[img] = 0u;  // pathological fallback
        if (above < (unsigned)TOPK && suf >= (unsigned)TOPK) {
            unsigned cum = above;
            for (int j = 3; j >= 0; --j) {
                cum += b4[j];
                if (cum >= (unsigned)TOPK) { P[img] = (unsigned)(lane * 4 + j); break; }
            }
        }
    }
}

// K2 (fused): bin-scan compaction -> key build -> bitonic sort -> decode ->
// soft-NMS (DPP-argmax, exact) -> inline greedy NMS -> top-100 emit.
__global__ __launch_bounds__(1024) void k_sortnms(const unsigned char* __restrict__ binc,
                                                  const unsigned* __restrict__ P,
                                                  const float* __restrict__ logits,
                                                  const float* __restrict__ rel,
                                                  const float* __restrict__ anch,
                                                  float* __restrict__ out, int A, int B) {
    __shared__ unsigned long long key[CANDMAX];
    __shared__ float s_box[TOPK][4];
    __shared__ int   s_lab[TOPK];
    __shared__ float s_pbox[TOPK][4];
    __shared__ int   s_plab[TOPK];
    __shared__ float s_psc[TOPK];
    __shared__ int   s_alive[TOPK];
    __shared__ unsigned s_n;

    const float CLIPV = 4.135166556742356f;  // log(1000/16)
    const float EPS = 1e-7f;
    const float W_ = 1333.0f, H_ = 800.0f;

    int img = blockIdx.x;
    int tid = threadIdx.x;
    const float* base = logits + (size_t)img * A * NCLS;

    // ---- compaction phase 1: scan bins, collect candidate anchor indices ----
    if (tid == 0) s_n = 0;
    __syncthreads();
    {
        unsigned p = P[img];
        unsigned psel = p ? (p - 1u) : 0u;
        const unsigned* b4 = (const unsigned*)(binc + (size_t)img * A);
        int nquad = A >> 2;
        int nq4 = nquad >> 2;
        for (int g = tid; g < nq4; g += 1024) {
            uint4 u = ((const uint4*)b4)[g];
            unsigned ws[4] = {u.x, u.y, u.z, u.w};
#pragma unroll
            for (int w2 = 0; w2 < 4; ++w2) {
                unsigned ub = ws[w2];
#pragma unroll
                for (int j = 0; j < 4; ++j) {
                    unsigned bj = (ub >> (8 * j)) & 0xFFu;
                    if ((psel == 0u) || (bj >= psel)) {
                        unsigned pos = atomicAdd(&s_n, 1u);
                        if (pos < CANDMAX)
                            key[pos] = (unsigned long long)(unsigned)((g * 4 + w2) * 4 + j);
                    }
                }
            }
        }
        for (int q = (nq4 << 2) + tid; q < nquad; q += 1024) {
            unsigned ub = b4[q];
#pragma unroll
            for (int j = 0; j < 4; ++j) {
                unsigned bj = (ub >> (8 * j)) & 0xFFu;
                if ((psel == 0u) || (bj >= psel)) {
                    unsigned pos = atomicAdd(&s_n, 1u);
                    if (pos < CANDMAX)
                        key[pos] = (unsigned long long)(unsigned)(q * 4 + j);
                }
            }
        }
        for (int a = (nquad << 2) + tid; a < A; a += 1024) {
            unsigned bj = binc[(size_t)img * A + a];
            if ((psel == 0u) || (bj >= psel)) {
                unsigned pos = atomicAdd(&s_n, 1u);
                if (pos < CANDMAX)
                    key[pos] = (unsigned long long)(unsigned)a;
            }
        }
    }
    __syncthreads();
    unsigned n = s_n;
    if (n > CANDMAX) n = CANDMAX;
    int L = (n <= 1024) ? 1024 : (n <= 2048) ? 2048 : CANDMAX;

    // ---- phase 2: gather logits, build exact keys; pad the rest ----
    for (int t2 = tid; t2 < (int)n; t2 += 1024) {
        unsigned a = (unsigned)key[t2];
        const float* lp = base + (size_t)a * NCLS;
        float m = lp[0];
#pragma unroll
        for (int c = 1; c < 10; ++c) m = fmaxf(m, lp[c]);
        float sc = sigmoidf_(m);           // == max(sigmoid(l_c)): monotone
        sc = (sc > 0.05f) ? sc : 0.0f;     // exact old gate for the key
        unsigned bits = __float_as_uint(sc);
        key[t2] = ((unsigned long long)(~bits) << 32) | a;
    }
    for (int i = (int)n + tid; i < CANDMAX; i += 1024) key[i] = ~0ull;
    __syncthreads();

    // ---- sort phase (ascending => best score first, then lowest index) ----
    for (int k = 2; k <= L; k <<= 1) {
        for (int j = k >> 1; j > 0; j >>= 1) {
            for (int i = tid; i < L; i += 1024) {
                int l = i ^ j;
                if (l > i) {
                    unsigned long long va = key[i], vb = key[l];
                    bool up = ((i & k) == 0);
                    if (up ? (va > vb) : (va < vb)) { key[i] = vb; key[l] = va; }
                }
            }
            __syncthreads();
        }
    }

    // ---- Phase A (1024 threads, 1 candidate each): decode into LDS ----
    if (tid < TOPK) {
        unsigned long long ik = key[tid];
        unsigned ai = (unsigned)ik;
        if (ai >= (unsigned)A) ai = 0;
        const float* lp = base + (size_t)ai * NCLS;
        float best = sigmoidf_(lp[0]); int lbb = 0;
#pragma unroll
        for (int cc = 1; cc < NCLS; ++cc) {
            float v = sigmoidf_(lp[cc]);
            if (v > best) { best = v; lbb = cc; }
        }
        const float* rp = rel + ((size_t)img * A + ai) * 4;
        const float* ap = anch + (size_t)ai * 4;
        float a0 = ap[0], a1 = ap[1], a2 = ap[2], a3 = ap[3];
        float wa = a2 - a0, ha = a3 - a1;
        float cxa = a0 + 0.5f * wa, cya = a1 + 0.5f * ha;
        float dx = rp[0], dy = rp[1];
        float dw = fminf(rp[2], CLIPV), dh = fminf(rp[3], CLIPV);
        float cx = dx * wa + cxa, cy = dy * ha + cya;
        float w = expf(dw) * wa, h = expf(dh) * ha;
        s_box[tid][0] = fminf(fmaxf(cx - 0.5f * w, 0.0f), W_);
        s_box[tid][1] = fminf(fmaxf(cy - 0.5f * h, 0.0f), H_);
        s_box[tid][2] = fminf(fmaxf(cx + 0.5f * w, 0.0f), W_);
        s_box[tid][3] = fminf(fmaxf(cy + 0.5f * h, 0.0f), H_);
        s_lab[tid] = lbb;
    }
    __syncthreads();
    if (tid >= 64) return;          // wave 0 only from here; no more barriers
    int lane = tid;

    int M = TOPK;
    int need_full = 0;
    float bound = key_score(key, ACTK);   // init score of first EXCLUDED cand

    // ================= FAST ATTEMPT: DPP-argmax, 4 slots =================
    {
        float sc[4], x1[4], y1[4], x2[4], y2[4], ar[4];
        int lb[4];
#pragma unroll
        for (int j = 0; j < 4; ++j) {
            int c = lane + (j << 6);
            float4 bb = *(const float4*)&s_box[c][0];
            x1[j] = bb.x; y1[j] = bb.y; x2[j] = bb.z; y2[j] = bb.w;
            ar[j] = (bb.z - bb.x) * (bb.w - bb.y);
            lb[j] = s_lab[c];
            sc[j] = key_score(key, c);
        }

        int nconf = 0, Mf = -1;

        for (int t = 0; t < ACTK; ++t) {
            float bv = sc[0]; int bj = 0;
#pragma unroll
            for (int j = 1; j < 4; ++j)
                if (sc[j] > bv) { bv = sc[j]; bj = j; }
            unsigned mk = fkey_(bv);
            unsigned mx = wave_umax_(mk);          // uniform SGPR result
            float pcur = funkey_(mx);

            if (!(pcur >= bound)) { need_full = 1; break; }

            // lowest-index winner: smallest slot j, then smallest lane (R12 form)
            int pick = -1;
#pragma unroll
            for (int jj = 0; jj < 4; ++jj) {
                if (pick < 0) {
                    unsigned long long mj = __ballot(mk == mx && bj == jj);
                    if (mj) pick = (jj << 6) + (__ffsll(mj) - 1);
                }
            }

            float psc = fmaxf(pcur, 0.0f);
            float4 pb = *(const float4*)&s_box[pick][0];
            int plab_ = s_lab[pick];
            if (lane == 0) {
                *(float4*)&s_pbox[t][0] = pb;
                s_plab[t] = plab_;
                s_psc[t] = psc;
            }

            // ---- greedy loads issued early (static unroll, clamped addrs) ----
            float4 qb[4]; int ga[4];
#pragma unroll
            for (int k = 0; k < 4; ++k) {
                int p = lane + (k << 6);
                int pc2 = (p < t) ? p : 0;
                qb[k] = *(const float4*)&s_pbox[pc2][0];
                ga[k] = (p < t) ? s_alive[pc2] : 0;
            }

            // ---- decay (ballot-skip: divide+expf only when a lane is hot) ----
            float wax = (pb.z - pb.x) * (pb.w - pb.y);
#pragma unroll
            for (int j = 0; j < 4; ++j) {
                float lx2 = fmaxf(pb.x, x1[j]), ly2 = fmaxf(pb.y, y1[j]);
                float rx2 = fminf(pb.z, x2[j]), ry2 = fminf(pb.w, y2[j]);
                float iw2 = fmaxf(rx2 - lx2, 0.0f), ih2 = fmaxf(ry2 - ly2, 0.0f);
                float inter2 = iw2 * ih2;
                bool hot = (inter2 > 0.0f) && (lb[j] == plab_);
                if (__ballot(hot) != 0ull) {
                    float iou2 = inter2 / (wax + ar[j] - inter2 + EPS);
                    float ie = (lb[j] == plab_) ? iou2 : 0.0f;
                    sc[j] *= expf(-(ie * ie) / 0.5f);
                }
                // skipped slots/lanes: factor would be expf(-0.0f)==1.0f exactly
            }
            // mark picked (after decay, matching the verified ordering)
#pragma unroll
            for (int j = 0; j < 4; ++j)
                if (lane + (j << 6) == pick) sc[j] = -1.0f;

            // ---- greedy compares + ballot (loads landed under decay) ----
            bool sup = false;
#pragma unroll
            for (int k = 0; k < 4; ++k) {
                if (ga[k]) {
                    float lx = fmaxf(pb.x, qb[k].x), ly = fmaxf(pb.y, qb[k].y);
                    float rx = fminf(pb.z, qb[k].z), ry = fminf(pb.w, qb[k].w);
                    float iw = fmaxf(rx - lx, 0.0f), ih = fmaxf(ry - ly, 0.0f);
                    float inter = iw * ih;
                    float qa = (qb[k].z - qb[k].x) * (qb[k].w - qb[k].y);
                    float iou = inter / (wax + qa - inter + EPS);
                    sup = sup || (iou > 0.8f);
                }
            }
            bool alive = (psc > 0.3f) && (__ballot(sup) == 0ull);
            if (lane == 0) s_alive[t] = alive ? 1 : 0;
            nconf += alive ? 1 : 0;
            if (nconf >= DETS) { Mf = t + 1; break; }
        }
        if (!need_full) {
            if (Mf < 0) need_full = 1;   // exhausted 256 picks with <100 dets
            else M = Mf;
        }
    }

    // ================= FULL FALLBACK: verbatim 16-slot loop =================
    if (need_full) {
        float sc[SLOTS], x1[SLOTS], y1[SLOTS], x2[SLOTS], y2[SLOTS], ar[SLOTS];
        int lb[SLOTS];
#pragma unroll
        for (int j = 0; j < SLOTS; ++j) {
            int c = lane + (j << 6);
            if (c < TOPK) {
                float4 bb = *(const float4*)&s_box[c][0];
                x1[j] = bb.x; y1[j] = bb.y; x2[j] = bb.z; y2[j] = bb.w;
                ar[j] = (bb.z - bb.x) * (bb.w - bb.y);
                lb[j] = s_lab[c];
                sc[j] = key_score(key, c);
            } else {
                sc[j] = -2.0f; lb[j] = -1;
                x1[j] = y1[j] = x2[j] = y2[j] = ar[j] = 0.0f;
            }
        }
        unsigned long long aw = 0;
        if (lane < 15) aw = ~0ull;
        else if (lane == 15) aw = (1ull << (TOPK - 15 * 64)) - 1;
        int f = 0, nconf = 0;
        M = TOPK;
        for (int t = 0; t < TOPK; ++t) {
            int fp = (f < TOPK) ? f : 0;
            float4 fb = *(const float4*)&s_box[fp][0];
            int flab = s_lab[fp];
            int fs = f >> 6;
            float v = sc[0];
#pragma unroll
            for (int j = 1; j < SLOTS; ++j) if (fs == j) v = sc[j];
            float cf = __shfl(v, f & 63);
            float lm = sc[0];
#pragma unroll
            for (int j = 1; j < SLOTS; ++j) lm = fmaxf(lm, sc[j]);
            int pick; float pcur; float4 pb; int plab_;
            unsigned long long bb2 = __ballot(lm > cf);
            if (bb2 == 0) {
                pick = f; pcur = cf; pb = fb; plab_ = flab;
            } else {
                float bv = sc[0]; int bi = lane;
#pragma unroll
                for (int j = 1; j < SLOTS; ++j) {
                    int e = lane + (j << 6);
                    if (sc[j] > bv) { bv = sc[j]; bi = e; }
                }
#pragma unroll
                for (int d = 32; d; d >>= 1) {
                    float ov = __shfl_xor(bv, d);
                    int oi = __shfl_xor(bi, d);
                    if (ov > bv || (ov == bv && oi < bi)) { bv = ov; bi = oi; }
                }
                pick = bi; pcur = bv;
                pb = *(const float4*)&s_box[pick][0];
                plab_ = s_lab[pick];
            }
            float psc = fmaxf(pcur, 0.0f);
            if (lane == 0) {
                *(float4*)&s_pbox[t][0] = pb;
                s_plab[t] = plab_;
                s_psc[t] = psc;
            }
            bool alive = (psc > 0.3f);
            if (alive && t > 0) {
                float pa = (pb.z - pb.x) * (pb.w - pb.y);
                int kprev = ((t - 1) >> 6) + 1;
                bool sup = false;
                for (int k = 0; k < kprev; ++k) {
                    int p = lane + (k << 6);
                    int pc = (p < t) ? p : 0;
                    float4 qb = *(const float4*)&s_pbox[pc][0];
                    int ga = s_alive[pc];
                    if (p < t && ga) {
                        float lx = fmaxf(pb.x, qb.x), ly = fmaxf(pb.y, qb.y);
                        float rx = fminf(pb.z, qb.z), ry = fminf(pb.w, qb.w);
                        float iw = fmaxf(rx - lx, 0.0f), ih = fmaxf(ry - ly, 0.0f);
                        float inter = iw * ih;
                        float qa = (qb.z - qb.x) * (qb.w - qb.y);
                        float iou = inter / (pa + qa - inter + EPS);
                        sup = sup || (iou > 0.8f);
                    }
                }
                alive = (__ballot(sup) == 0ull);
            }
            if (lane == 0) s_alive[t] = alive ? 1 : 0;
            nconf += alive ? 1 : 0;
            if (nconf >= DETS) { M = t + 1; break; }
            float wax = (pb.z - pb.x) * (pb.w - pb.y);
#pragma unroll
            for (int j = 0; j < SLOTS; ++j) {
                float lx2 = fmaxf(pb.x, x1[j]), ly2 = fmaxf(pb.y, y1[j]);
                float rx2 = fminf(pb.z, x2[j]), ry2 = fminf(pb.w, y2[j]);
                float iw2 = fmaxf(rx2 - lx2, 0.0f), ih2 = fmaxf(ry2 - ly2, 0.0f);
                float inter2 = iw2 * ih2;
                bool hot = (inter2 > 0.0f) && (lb[j] == plab_);
                if (__ballot(hot) != 0ull) {
                    float iou2 = inter2 / (wax + ar[j] - inter2 + EPS);
                    float ie = (lb[j] == plab_) ? iou2 : 0.0f;
                    sc[j] *= expf(-(ie * ie) / 0.5f);
                }
            }
#pragma unroll
            for (int j = 0; j < SLOTS; ++j)
                if (lane + (j << 6) == pick) sc[j] = -1.0f;
            if (lane == (pick >> 6)) aw &= ~(1ull << (pick & 63));
            if (pick == f) {
                int fw = f >> 6;
                unsigned long long w2 = __shfl(aw, fw);
                while (w2 == 0ull && fw < 15) { ++fw; w2 = __shfl(aw, fw); }
                f = (w2 == 0ull) ? TOPK : (fw << 6) + (__ffsll(w2) - 1);
            }
        }
    }

    // ---- emit: alive picks in pick order, then dead padding if needed ----
    float* out_boxes  = out;
    float* out_scores = out + (size_t)B * DETS * 4;
    float* out_labels = out + (size_t)B * DETS * 5;
    int kmax = (M + 63) >> 6;
    int base2 = 0;
    for (int k = 0; k < kmax; ++k) {
        int p = lane + (k << 6);
        bool av = (p < M) && (s_alive[p] != 0);
        unsigned long long mask = __ballot(av);
        int slot = base2 + (int)__popcll(mask & ((1ull << lane) - 1ull));
        if (av && slot < DETS) {
            float4 pb = *(const float4*)&s_pbox[p][0];
            float* ob = out_boxes + ((size_t)img * DETS + slot) * 4;
            ob[0] = pb.x; ob[1] = pb.y; ob[2] = pb.z; ob[3] = pb.w;
            out_scores[img * DETS + slot] = s_psc[p];
            out_labels[img * DETS + slot] = (float)s_plab[p];
        }
        base2 += (int)__popcll(mask);
    }
    if (base2 < DETS) {
        int dbase = 0;
        for (int k = 0; k < kmax; ++k) {
            int p = lane + (k << 6);
            bool dd = (p < M) && (s_alive[p] == 0);
            unsigned long long mask = __ballot(dd);
            int slot = base2 + dbase + (int)__popcll(mask & ((1ull << lane) - 1ull));
            if (dd && slot < DETS) {
                float4 pb = *(const float4*)&s_pbox[p][0];
                float* ob = out_boxes + ((size_t)img * DETS + slot) * 4;
                ob[0] = pb.x; ob[1] = pb.y; ob[2] = pb.z; ob[3] = pb.w;
                out_scores[img * DETS + slot] = -1.0f;
                out_labels[img * DETS + slot] = (float)s_plab[p];
            }
            dbase += (int)__popcll(mask);
        }
    }
}

extern "C" void kernel_launch(void* const* d_in, const int* in_sizes, int n_in,
                              void* d_out, int out_size, void* d_ws, size_t ws_size,
                              hipStream_t stream) {
    const float* logits = (const float*)d_in[0];
    const float* rel = (const float*)d_in[1];
    const float* anch = (const float*)d_in[2];
    float* out = (float*)d_out;

    int A = in_sizes[2] / 4;                 // anchors
    int B = in_sizes[0] / (A * NCLS);        // batch

    // workspace: [hist | done] zeroed in ONE memset; then P, bins (~1.6MB).
    char* w = (char*)d_ws;
    unsigned* hist = (unsigned*)w;           w += (size_t)B * NB2 * 4;
    unsigned* done = (unsigned*)w;           w += (size_t)B * 4;
    size_t zbytes = (size_t)(w - (char*)d_ws);
    unsigned* P = (unsigned*)w;              w += (size_t)B * 4;
    unsigned char* binc = (unsigned char*)w;

    hipMemsetAsync(d_ws, 0, zbytes, stream);

    dim3 g1(NBLKB, (unsigned)B);
    k_score_bins<<<g1, 256, 0, stream>>>(logits, binc, hist, done, P, A);
    k_sortnms<<<B, 1024, 0, stream>>>(binc, P, logits, rel, anch, out, A, B);
}